// Round 1
// 7882.871 us; speedup vs baseline: 1.1713x; 1.1713x over previous
//
#include <hip/hip_runtime.h>

typedef __attribute__((ext_vector_type(8))) short short8;
typedef __attribute__((ext_vector_type(4))) float f32x4;
typedef __attribute__((ext_vector_type(4))) unsigned int uint4v;
typedef unsigned short u16;

#define DEVI static __device__ __forceinline__

constexpr int TTm = 64;     // seq len (src & tgt)
constexpr int BBm = 64;     // batch
constexpr int EEm = 512;    // embed dim
constexpr int HHm = 1024;   // hidden
constexpr int GGm = 4096;   // 4*H
constexpr int TDm = 63;     // decoder steps

// ---------- small helpers ----------
DEVI u16 f2b(float f) {  // fp32 -> bf16 RNE
  unsigned u = __builtin_bit_cast(unsigned, f);
  return (u16)((u + 0x7fffu + ((u >> 16) & 1u)) >> 16);
}
DEVI float b2f(u16 h) { return __builtin_bit_cast(float, (unsigned)h << 16); }
DEVI float sigm(float x) { return 1.0f / (1.0f + __expf(-x)); }
DEVI float tanh_(float x) { return 1.0f - 2.0f / (1.0f + __expf(2.0f * x)); }

DEVI short8 cvt8(const float* p) {
  f32x4 x0 = *(const f32x4*)p;
  f32x4 x1 = *(const f32x4*)(p + 4);
  short8 r;
#pragma unroll
  for (int i = 0; i < 4; ++i) { r[i] = (short)f2b(x0[i]); r[i + 4] = (short)f2b(x1[i]); }
  return r;
}
DEVI void stage32_f32(short* dst, const float* src) {
#pragma unroll
  for (int i = 0; i < 4; ++i) *(short8*)&dst[i * 8] = cvt8(src + i * 8);
}
DEVI void stage32_b16(short* dst, const u16* src) {
#pragma unroll
  for (int i = 0; i < 4; ++i) *(uint4v*)&dst[i * 8] = *(const uint4v*)(src + i * 8);
}

// system-scope write-through 2B store: visible agent-wide once vmcnt retires.
// Replaces the agent release-fence (whole-L2 writeback) for cross-block data.
DEVI void st_sys_b16(u16* p, u16 v) {
  unsigned d = v;
  asm volatile("global_store_short %0, %1, off sc0 sc1" :: "v"(p), "v"(d) : "memory");
}

// ---------- fence-free grid barrier ----------
// Cross-block data is published with sc0/sc1 write-through stores; consumers read
// at FRESH addresses each step (time-rotated slots), so no cache invalidate is
// needed. Flags use relaxed agent atomics (bypass L2 — proven by the poll working).
DEVI void gbar(unsigned* flags, unsigned phase) {
  // each wave drains its own vmem queue: sc0/sc1 stores are at LLC after this
  asm volatile("s_waitcnt vmcnt(0)" ::: "memory");
  __syncthreads();
  if (threadIdx.x == 0) {
    __hip_atomic_store(&flags[blockIdx.x * 16], phase, __ATOMIC_RELAXED,
                       __HIP_MEMORY_SCOPE_AGENT);
  }
  if (threadIdx.x < 64) {
    const int i0 = threadIdx.x * 4;
    for (;;) {
      int ok = 1;
#pragma unroll
      for (int i = 0; i < 4; ++i) {
        unsigned v = __hip_atomic_load(&flags[(i0 + i) * 16], __ATOMIC_RELAXED,
                                       __HIP_MEMORY_SCOPE_AGENT);
        ok &= (v >= phase);
      }
      if (__all(ok)) break;
      __builtin_amdgcn_s_sleep(1);
    }
  }
  asm volatile("" ::: "memory");  // compiler barrier: no hoisting loads above the poll
  __syncthreads();
}

// one BK=64 step of a 64x64 tile; 2 waves, wave wv owns cols [wv*32, wv*32+32)
DEVI void mfma_bk64(const short* As, const short* Bs, f32x4 acc[4][2], int wv, int ln) {
  const int l15 = ln & 15;
#pragma unroll
  for (int ks = 0; ks < 64; ks += 32) {
    const int kq = ks + ((ln >> 4) << 3);
    short8 b0 = *(const short8*)&Bs[(wv * 32 + l15) * 72 + kq];
    short8 b1 = *(const short8*)&Bs[(wv * 32 + 16 + l15) * 72 + kq];
#pragma unroll
    for (int mt = 0; mt < 4; ++mt) {
      short8 a = *(const short8*)&As[(mt * 16 + l15) * 72 + kq];
      acc[mt][0] = __builtin_amdgcn_mfma_f32_16x16x32_bf16(a, b0, acc[mt][0], 0, 0, 0);
      acc[mt][1] = __builtin_amdgcn_mfma_f32_16x16x32_bf16(a, b1, acc[mt][1], 0, 0, 0);
    }
  }
}

// ---------- setup ----------
__global__ void k_zero(uint4v* p, int n16) {
  int i = blockIdx.x * blockDim.x + threadIdx.x;
  uint4v z = {0u, 0u, 0u, 0u};
  for (; i < n16; i += gridDim.x * blockDim.x) p[i] = z;
}

__global__ void k_cvt_all(const float* Wihf, const float* Wihb, const float* Whhf,
                          const float* Whhb, const float* Wihd, const float* Whhd,
                          const float* Watt, const float* Whp, const float* Wcp,
                          const float* Wcomb, const float* Wvoc,
                          u16* o_ihf, u16* o_ihb, u16* o_hhf, u16* o_hhb,
                          u16* o_cat1, u16* o_cat2,
                          u16* o_att, u16* o_hp, u16* o_cp, u16* o_comb, u16* o_voc) {
  long i = (long)blockIdx.x * blockDim.x + threadIdx.x;
  const long stride = (long)gridDim.x * blockDim.x;
  for (; i < 65273856L; i += stride) {
    long r = i;
    if (r < 2097152) { o_ihf[r] = f2b(Wihf[r]); continue; } r -= 2097152;
    if (r < 2097152) { o_ihb[r] = f2b(Wihb[r]); continue; } r -= 2097152;
    if (r < 4194304) { o_hhf[r] = f2b(Whhf[r]); continue; } r -= 4194304;
    if (r < 4194304) { o_hhb[r] = f2b(Whhb[r]); continue; } r -= 4194304;
    if (r < 2097152) {  // cat1: W_ih_d[:, 0:512]
      long g = r >> 9, c = r & 511;
      o_cat1[r] = f2b(Wihd[g * 1536 + c]); continue;
    } r -= 2097152;
    if (r < 8388608) {  // cat2 row g = [W_ih_d[g][512:1536] | W_hh_d[g][:]]
      long g = r >> 11, c = r & 2047;
      o_cat2[r] = f2b(c < 1024 ? Wihd[g * 1536 + 512 + c] : Whhd[g * 1024 + (c - 1024)]);
      continue;
    } r -= 8388608;
    if (r < 2097152) { o_att[r] = f2b(Watt[r]); continue; } r -= 2097152;
    if (r < 2097152) { o_hp[r] = f2b(Whp[r]); continue; } r -= 2097152;
    if (r < 2097152) { o_cp[r] = f2b(Wcp[r]); continue; } r -= 2097152;
    if (r < 3145728) { o_comb[r] = f2b(Wcomb[r]); continue; } r -= 3145728;
    o_voc[r] = f2b(Wvoc[r]);
  }
}

// ---------- input-precompute: pre = emb[tok] @ W^T + bi + bh  (grid = (T, 64)) ----------
__global__ __launch_bounds__(128) void k_pre(
    const int* tok, const float* emb, const u16* W,
    const float* bi, const float* bh, u16* pre) {
  __shared__ short As[64 * 72], Bs[64 * 72];
  const int rt = blockIdx.x, ct = blockIdx.y;
  const int tid = threadIdx.x, wv = tid >> 6, sr = tid & 63, seg = tid >> 6;
  const int token = tok[rt * 64 + sr];
  const float* arow = emb + (long)token * EEm;
  const u16* brow = W + (long)(ct * 64 + sr) * EEm;
  f32x4 acc[4][2] = {};
  for (int k0 = 0; k0 < EEm; k0 += 64) {
    __syncthreads();
    stage32_f32(&As[sr * 72 + seg * 32], arow + k0 + seg * 32);
    stage32_b16(&Bs[sr * 72 + seg * 32], brow + k0 + seg * 32);
    __syncthreads();
    mfma_bk64(As, Bs, acc, wv, sr);
  }
  const int l15 = sr & 15, q = sr >> 4;
#pragma unroll
  for (int nt = 0; nt < 2; ++nt) {
    const int col = ct * 64 + wv * 32 + nt * 16 + l15;
    const float bias = bi[col] + bh[col];
#pragma unroll
    for (int mt = 0; mt < 4; ++mt)
#pragma unroll
      for (int r = 0; r < 4; ++r)
        pre[(long)(rt * 64 + mt * 16 + q * 4 + r) * GGm + col] = f2b(acc[mt][nt][r] + bias);
  }
}

// ---------- plain NT GEMM: C[M x (gridDim.y*64)] = A(bf16) * B(bf16,ldb)^T ----------
template <bool OUTB16>
__global__ __launch_bounds__(128) void k_gemm_plain(const u16* A, const u16* Bm,
                                                    void* C, int K, int ldb) {
  __shared__ short As[64 * 72], Bs[64 * 72];
  const int rt = blockIdx.x, ct = blockIdx.y;
  const int tid = threadIdx.x, wv = tid >> 6, sr = tid & 63, seg = tid >> 6;
  const u16* arow = A + (long)(rt * 64 + sr) * K;
  const u16* brow = Bm + (long)(ct * 64 + sr) * ldb;
  f32x4 acc[4][2] = {};
  for (int k0 = 0; k0 < K; k0 += 64) {
    __syncthreads();
    stage32_b16(&As[sr * 72 + seg * 32], arow + k0 + seg * 32);
    stage32_b16(&Bs[sr * 72 + seg * 32], brow + k0 + seg * 32);
    __syncthreads();
    mfma_bk64(As, Bs, acc, wv, sr);
  }
  const int l15 = sr & 15, q = sr >> 4, ldc = gridDim.y * 64;
#pragma unroll
  for (int nt = 0; nt < 2; ++nt) {
    const int col = ct * 64 + wv * 32 + nt * 16 + l15;
#pragma unroll
    for (int mt = 0; mt < 4; ++mt)
#pragma unroll
      for (int r = 0; r < 4; ++r) {
        const long idx = (long)(rt * 64 + mt * 16 + q * 4 + r) * ldc + col;
        if (OUTB16) ((u16*)C)[idx] = f2b(acc[mt][nt][r]);
        else        ((float*)C)[idx] = acc[mt][nt][r];
      }
  }
}

// ---------- cooperative encoder: all 64 time steps, both directions ----------
// h rotates through 64 time-indexed slots (slot s = h before step s): every
// consumer load is first-touch -> plain cached loads are never stale.
__global__ __launch_bounds__(256) void k_enc_all(
    const u16* __restrict__ Whhf, const u16* __restrict__ Whhb,
    const u16* __restrict__ pre_f, const u16* __restrict__ pre_b,
    const int* __restrict__ lens,
    u16* hist_f, u16* hist_b, u16* ench, u16* hcat, u16* ccat, unsigned* bar) {
  __shared__ float gshE[4 * 64 * 33];  // per-wave K-partials
  const int blk = blockIdx.x;
  const int dir = blk >> 7, jt = blk & 127, j0 = jt * 8;
  const u16* Whh = dir ? Whhb : Whhf;
  const u16* pre = dir ? pre_b : pre_f;
  u16* hist = dir ? hist_b : hist_f;
  const int tid = threadIdx.x, wv = tid >> 6, ln = tid & 63;
  const int l15 = ln & 15, half = ln >> 4;
  // B fragments: wave wv owns ksteps i*4+wv, i in 0..7 (K=1024 -> 32 ksteps)
  short8 bf[8][2];
#pragma unroll
  for (int i = 0; i < 8; ++i) {
    const int k = (i * 4 + wv) * 32 + half * 8;
#pragma unroll
    for (int nt = 0; nt < 2; ++nt) {
      const int n = nt * 16 + l15, g = n >> 3, jj = n & 7;
      bf[i][nt] = *(const short8*)(Whh + (long)(g * 1024 + j0 + jj) * 1024 + k);
    }
  }
  const int cb = tid & 63, cj = tid >> 6;  // cell: (batch cb, cols cj & cj+4)
  const int len_b = lens[cb];
  float creg[2] = {0.f, 0.f};
  u16 hlast[2] = {0, 0};
  for (int s = 0; s < 64; ++s) {
    const int t = dir ? (63 - s) : s;
    const u16* hcur = hist + s * 65536;
    u16* hnxt = hist + (s + 1) * 65536;
    f32x4 acc[4][2] = {};
#pragma unroll
    for (int i = 0; i < 8; ++i) {
      const int k = (i * 4 + wv) * 32 + half * 8;
#pragma unroll
      for (int mt = 0; mt < 4; ++mt) {
        short8 a = *(const short8*)(hcur + (mt * 16 + l15) * 1024 + k);
        acc[mt][0] = __builtin_amdgcn_mfma_f32_16x16x32_bf16(a, bf[i][0], acc[mt][0], 0, 0, 0);
        acc[mt][1] = __builtin_amdgcn_mfma_f32_16x16x32_bf16(a, bf[i][1], acc[mt][1], 0, 0, 0);
      }
    }
    __syncthreads();
#pragma unroll
    for (int mt = 0; mt < 4; ++mt)
#pragma unroll
      for (int nt = 0; nt < 2; ++nt)
#pragma unroll
        for (int r = 0; r < 4; ++r)
          gshE[wv * 2112 + (mt * 16 + half * 4 + r) * 33 + nt * 16 + l15] = acc[mt][nt][r];
    __syncthreads();
#pragma unroll
    for (int u = 0; u < 2; ++u) {
      const int jj = cj + u * 4, j = j0 + jj;
      float g4[4];
#pragma unroll
      for (int g = 0; g < 4; ++g) {
        const int n = g * 8 + jj;
        float v = gshE[cb * 33 + n] + gshE[2112 + cb * 33 + n] +
                  gshE[2 * 2112 + cb * 33 + n] + gshE[3 * 2112 + cb * 33 + n];
        v += b2f(pre[((long)t * 64 + cb) * GGm + g * 1024 + j]);
        g4[g] = v;
      }
      const float cold = creg[u];
      const float c2 = sigm(g4[1]) * cold + sigm(g4[0]) * tanh_(g4[2]);
      const float h2 = sigm(g4[3]) * tanh_(c2);
      const bool m = t < len_b;
      creg[u] = m ? c2 : cold;
      const u16 hv = m ? f2b(h2) : hcur[cb * 1024 + j];  // hcur line is L2-hot (A-loads)
      if (s < 63) st_sys_b16(&hnxt[cb * 1024 + j], hv);  // write-through publish
      else        hlast[u] = hv;                         // final h kept in regs
      ench[((long)cb * 64 + t) * 2048 + dir * 1024 + j] = f2b(m ? h2 : 0.f);
    }
    if (s < 63) gbar(bar, s + 1);
  }
  // epilogue: final states from registers — no post-loop coherence needed
#pragma unroll
  for (int u = 0; u < 2; ++u) {
    const int j = j0 + cj + u * 4;
    hcat[cb * 2048 + dir * 1024 + j] = hlast[u];
    ccat[cb * 2048 + dir * 1024 + j] = f2b(creg[u]);
  }
}

// ---------- cooperative decoder: all 63 steps, 2 barriers/step ----------
// h_hist slot t   = decoder h entering step t   (slot 0 = h0 from k_gemm_plain)
// o_hist slot t   = O entering step t           (slot 0 = zeros)
// o_hist slot t+1 doubles as outs[t] for the vocab kernels.
__global__ __launch_bounds__(256) void k_dec_all(
    const u16* __restrict__ Wcat2, const u16* __restrict__ Wcomb,
    const u16* __restrict__ y_pre, const u16* __restrict__ eproj,
    const u16* __restrict__ encW, const int* __restrict__ lens,
    u16* h_hist, const float* c_d, u16* o_hist, unsigned* bar) {
  __shared__ float gsh[4 * 64 * 17];
  __shared__ float h2s[1024];
  __shared__ float part[256];
  __shared__ float alph[64];
  const int blk = blockIdx.x, tid = threadIdx.x, wv = tid >> 6, ln = tid & 63;
  const int l15 = ln & 15, half = ln >> 4;
  const int j0 = blk * 4;
  // gates B-frags: K=2048 -> 64 ksteps, 16 per wave
  short8 bg[16];
#pragma unroll
  for (int i = 0; i < 16; ++i) {
    const int k = (i * 4 + wv) * 32 + half * 8;
    const int g = l15 >> 2, jj = l15 & 3;
    bg[i] = *(const short8*)(Wcat2 + (long)(g * 1024 + j0 + jj) * 2048 + k);
  }
  const int cb = tid & 63, cj = tid >> 6;  // (batch cb, col cj)
  const int ab = blk & 63, aq = blk >> 6;  // A' assignment
  const int len_ab = lens[ab];
  float creg = c_d[cb * 1024 + j0 + cj];
  unsigned phase = 0;
  for (int t = 0; t < TDm; ++t) {
    const u16* hprev = h_hist + t * 65536;
    u16* hnew = h_hist + (t + 1) * 65536;
    const u16* o_prev = o_hist + t * 65536;
    u16* o_out = o_hist + (t + 1) * 65536;
    // ---- phase G: gates GEMM + cell ----
    f32x4 acc[4] = {};
#pragma unroll
    for (int i = 0; i < 16; ++i) {
      const int k = (i * 4 + wv) * 32 + half * 8;
      const u16* asrc = (k < 1024) ? (o_prev + k) : (hprev + (k - 1024));
#pragma unroll
      for (int mt = 0; mt < 4; ++mt) {
        short8 a = *(const short8*)(asrc + (mt * 16 + l15) * 1024);
        acc[mt] = __builtin_amdgcn_mfma_f32_16x16x32_bf16(a, bg[i], acc[mt], 0, 0, 0);
      }
    }
    __syncthreads();
#pragma unroll
    for (int mt = 0; mt < 4; ++mt)
#pragma unroll
      for (int r = 0; r < 4; ++r)
        gsh[wv * 1088 + (mt * 16 + half * 4 + r) * 17 + l15] = acc[mt][r];
    __syncthreads();
    {
      float g4[4];
#pragma unroll
      for (int g = 0; g < 4; ++g) {
        const int n = g * 4 + cj;
        float v = gsh[cb * 17 + n] + gsh[1088 + cb * 17 + n] +
                  gsh[2 * 1088 + cb * 17 + n] + gsh[3 * 1088 + cb * 17 + n];
        v += b2f(y_pre[((long)t * 64 + cb) * GGm + g * 1024 + j0 + cj]);
        g4[g] = v;
      }
      const float c2 = sigm(g4[1]) * creg + sigm(g4[0]) * tanh_(g4[2]);
      const float h2 = sigm(g4[3]) * tanh_(c2);
      creg = c2;
      st_sys_b16(&hnew[cb * 1024 + j0 + cj], f2b(h2));  // write-through publish
    }
    gbar(bar, ++phase);
    // ---- phase A': attention + combine + tanh ----
    for (int i = tid; i < 1024; i += 256) h2s[i] = b2f(hnew[ab * 1024 + i]);
    __syncthreads();
    {  // scores (redundant across the 4 q-blocks of batch ab)
      const int tt = tid >> 2, qq = tid & 3;
      const u16* row = eproj + ((long)ab * 64 + tt) * 1024 + qq * 256;
      float a0 = 0.f;
      for (int i = 0; i < 256; i += 8) {
        uint4v v = *(const uint4v*)(row + i);
        const u16* pv = (const u16*)&v;
#pragma unroll
        for (int j = 0; j < 8; ++j) a0 += b2f(pv[j]) * h2s[qq * 256 + i + j];
      }
      part[tid] = a0;
    }
    __syncthreads();
    if (tid < 64) {
      float e = part[tid * 4] + part[tid * 4 + 1] + part[tid * 4 + 2] + part[tid * 4 + 3];
      e = (tid < len_ab) ? e : -INFINITY;
      float mx = e;
#pragma unroll
      for (int m = 1; m < 64; m <<= 1) mx = fmaxf(mx, __shfl_xor(mx, m));
      float p = __expf(e - mx);
      float s = p;
#pragma unroll
      for (int m = 1; m < 64; m <<= 1) s += __shfl_xor(s, m);
      alph[tid] = p / s;
    }
    __syncthreads();
    {
      const int j = aq * 256 + tid;
      float oa = 0.f;
      for (int tt = 0; tt < 64; ++tt) {
        const float al = alph[tt];
        if (al != 0.f) oa += al * b2f(encW[((long)ab * 64 + tt) * 1024 + j]);
      }
      float oh = 0.f;
      const u16* wrow = Wcomb + (long)j * 3072 + 2048;
      for (int k = 0; k < 1024; k += 8) {
        uint4v v = *(const uint4v*)(wrow + k);
        const u16* pv = (const u16*)&v;
#pragma unroll
        for (int jj = 0; jj < 8; ++jj) oh += b2f(pv[jj]) * h2s[k + jj];
      }
      const u16 ob = f2b(tanh_(oa + oh));
      st_sys_b16(&o_out[ab * 1024 + j], ob);  // single store: O state + outs[t]
    }
    if (t < TDm - 1) gbar(bar, ++phase);
  }
}

// ---------- vocab projection: streaming sum(exp(logit)) ----------
__global__ __launch_bounds__(128) void k_vocab(const u16* outs, const u16* Wvoc,
                                               float* sumexp) {
  __shared__ short As[64 * 72], Bs[64 * 72];
  const int vt = blockIdx.x, t = blockIdx.y;
  const int tid = threadIdx.x, wv = tid >> 6, sr = tid & 63, seg = tid >> 6;
  const u16* arow = outs + ((long)t * 64 + sr) * 1024;
  const u16* brow = Wvoc + (long)(vt * 64 + sr) * 1024;
  f32x4 acc[4][2] = {};
  for (int k0 = 0; k0 < 1024; k0 += 64) {
    __syncthreads();
    stage32_b16(&As[sr * 72 + seg * 32], arow + k0 + seg * 32);
    stage32_b16(&Bs[sr * 72 + seg * 32], brow + k0 + seg * 32);
    __syncthreads();
    mfma_bk64(As, Bs, acc, wv, sr);
  }
  const int l15 = sr & 15, q = sr >> 4;
#pragma unroll
  for (int mt = 0; mt < 4; ++mt)
#pragma unroll
    for (int r = 0; r < 4; ++r) {
      float e = __expf(acc[mt][0][r]) + __expf(acc[mt][1][r]);
      e += __shfl_xor(e, 1); e += __shfl_xor(e, 2);
      e += __shfl_xor(e, 4); e += __shfl_xor(e, 8);
      if (l15 == 0) atomicAdd(&sumexp[t * 64 + mt * 16 + q * 4 + r], e);
    }
}

__global__ __launch_bounds__(256) void k_gold(const u16* outs, const u16* Wvoc,
                                              const int* tgt, float* gold) {
  const int t = blockIdx.x;
  const int wv = threadIdx.x >> 6, ln = threadIdx.x & 63;
  for (int b = wv; b < 64; b += 4) {
    const int g = tgt[(t + 1) * 64 + b];
    const u16* o = outs + ((long)t * 64 + b) * 1024 + ln * 16;
    const u16* w = Wvoc + (long)g * 1024 + ln * 16;
    uint4v v0 = *(const uint4v*)o, v1 = *(const uint4v*)(o + 8);
    uint4v w0 = *(const uint4v*)w, w1 = *(const uint4v*)(w + 8);
    const u16 *pv0 = (const u16*)&v0, *pv1 = (const u16*)&v1;
    const u16 *pw0 = (const u16*)&w0, *pw1 = (const u16*)&w1;
    float acc = 0.f;
#pragma unroll
    for (int j = 0; j < 8; ++j)
      acc += b2f(pv0[j]) * b2f(pw0[j]) + b2f(pv1[j]) * b2f(pw1[j]);
#pragma unroll
    for (int m = 1; m < 64; m <<= 1) acc += __shfl_xor(acc, m);
    if (ln == 0) gold[t * 64 + b] = acc;
  }
}

__global__ void k_final(const float* gold, const float* sumexp, const int* tgt,
                        float* out) {
  const int b = threadIdx.x;
  float s = 0.f;
  for (int t = 0; t < TDm; ++t)
    if (tgt[(t + 1) * 64 + b] != 0)
      s += gold[t * 64 + b] - logf(sumexp[t * 64 + b]);
  out[b] = s;
}

// ---------- host ----------
extern "C" void kernel_launch(void* const* d_in, const int* in_sizes, int n_in,
                              void* d_out, int out_size, void* d_ws, size_t ws_size,
                              hipStream_t stream) {
  const int* src_tok = (const int*)d_in[0];
  const int* tgt_tok = (const int*)d_in[1];
  const int* lens    = (const int*)d_in[2];
  const float* semb  = (const float*)d_in[3];
  const float* demb  = (const float*)d_in[4];
  const float* Wihf  = (const float*)d_in[5];
  const float* Whhf  = (const float*)d_in[6];
  const float* bihf  = (const float*)d_in[7];
  const float* bhhf  = (const float*)d_in[8];
  const float* Wihb  = (const float*)d_in[9];
  const float* Whhb  = (const float*)d_in[10];
  const float* bihb  = (const float*)d_in[11];
  const float* bhhb  = (const float*)d_in[12];
  const float* Wihd  = (const float*)d_in[13];
  const float* Whhd  = (const float*)d_in[14];
  const float* bihd  = (const float*)d_in[15];
  const float* bhhd  = (const float*)d_in[16];
  const float* Whp   = (const float*)d_in[17];
  const float* Wcp   = (const float*)d_in[18];
  const float* Watt  = (const float*)d_in[19];
  const float* Wcomb = (const float*)d_in[20];
  const float* Wvoc  = (const float*)d_in[21];

  char* w = (char*)d_ws;
  auto alloc = [&](size_t bytes) { char* p = w; w += (bytes + 255) & ~(size_t)255; return p; };
  // zero-span (contiguous): encoder h histories, decoder o history, sume, barriers
  u16* histF  = (u16*)alloc(8388608);    // 64 slots x (64x1024) bf16; slot0 = h=0
  u16* histB  = (u16*)alloc(8388608);
  u16* o_hist = (u16*)alloc(8388608);    // 64 slots; slot0 = O(-1)=0; slot t+1 = outs[t]
  float* sume = (float*)alloc(16384);
  unsigned* barE = (unsigned*)alloc(16384);   // 256 flags x 64B
  unsigned* barD = (unsigned*)alloc(16384);
  const int zero16 = (int)((w - (char*)histF) / 16);
  float* gold   = (float*)alloc(16384);
  float* c_d    = (float*)alloc(262144);
  u16* h_hist   = (u16*)alloc(8388608);  // decoder h: 64 slots; slot0 = h0
  u16* hcat     = (u16*)alloc(262144);
  u16* ccat     = (u16*)alloc(262144);
  u16* Wb_ihf   = (u16*)alloc(4194304);
  u16* Wb_ihb   = (u16*)alloc(4194304);
  u16* Wb_hhf   = (u16*)alloc(8388608);
  u16* Wb_hhb   = (u16*)alloc(8388608);
  u16* Wb_cat1  = (u16*)alloc(4194304);
  u16* Wb_cat2  = (u16*)alloc(16777216);
  u16* Wb_att   = (u16*)alloc(4194304);
  u16* Wb_hp    = (u16*)alloc(4194304);
  u16* Wb_cp    = (u16*)alloc(4194304);
  u16* Wb_comb  = (u16*)alloc(6291456);
  u16* Wb_voc   = (u16*)alloc(65536000);
  u16* pre_f    = (u16*)alloc(33554432);
  u16* pre_b    = (u16*)alloc(33554432);
  u16* y_pre    = (u16*)alloc(33030144);  // 63*64*4096 bf16
  u16* ench     = (u16*)alloc(16777216);  // (b, t, 2048) bf16
  u16* eproj    = (u16*)alloc(8388608);   // (b, t, 1024) bf16
  u16* encW     = (u16*)alloc(8388608);   // (b, t, 1024) bf16
  u16* outs     = o_hist + 65536;         // view: slot t+1 of o_hist = outs[t]

  k_zero<<<dim3(256), dim3(256), 0, stream>>>((uint4v*)histF, zero16);
  k_cvt_all<<<dim3(2048), dim3(256), 0, stream>>>(
      Wihf, Wihb, Whhf, Whhb, Wihd, Whhd, Watt, Whp, Wcp, Wcomb, Wvoc,
      Wb_ihf, Wb_ihb, Wb_hhf, Wb_hhb, Wb_cat1, Wb_cat2,
      Wb_att, Wb_hp, Wb_cp, Wb_comb, Wb_voc);
  k_pre<<<dim3(64, 64), dim3(128), 0, stream>>>(src_tok, semb, Wb_ihf, bihf, bhhf, pre_f);
  k_pre<<<dim3(64, 64), dim3(128), 0, stream>>>(src_tok, semb, Wb_ihb, bihb, bhhb, pre_b);
  k_pre<<<dim3(63, 64), dim3(128), 0, stream>>>(tgt_tok, demb, Wb_cat1, bihd, bhhd, y_pre);
  {
    void* args[] = {(void*)&Wb_hhf, (void*)&Wb_hhb, (void*)&pre_f, (void*)&pre_b,
                    (void*)&lens, (void*)&histF, (void*)&histB, (void*)&ench,
                    (void*)&hcat, (void*)&ccat, (void*)&barE};
    hipLaunchCooperativeKernel((void*)k_enc_all, dim3(256), dim3(256), args, 0, stream);
  }
  k_gemm_plain<true><<<dim3(1, 16), dim3(128), 0, stream>>>(hcat, Wb_hp, (void*)h_hist, 2048, 2048);
  k_gemm_plain<false><<<dim3(1, 16), dim3(128), 0, stream>>>(ccat, Wb_cp, (void*)c_d, 2048, 2048);
  k_gemm_plain<true><<<dim3(64, 16), dim3(128), 0, stream>>>(ench, Wb_att, (void*)eproj, 2048, 2048);
  k_gemm_plain<true><<<dim3(64, 16), dim3(128), 0, stream>>>(ench, Wb_comb, (void*)encW, 2048, 3072);
  {
    void* args[] = {(void*)&Wb_cat2, (void*)&Wb_comb, (void*)&y_pre, (void*)&eproj,
                    (void*)&encW, (void*)&lens, (void*)&h_hist, (void*)&c_d,
                    (void*)&o_hist, (void*)&barD};
    hipLaunchCooperativeKernel((void*)k_dec_all, dim3(256), dim3(256), args, 0, stream);
  }
  k_vocab<<<dim3(500, 63), dim3(128), 0, stream>>>(outs, Wb_voc, sume);
  k_gold<<<dim3(63), dim3(256), 0, stream>>>(outs, Wb_voc, tgt_tok, gold);
  k_final<<<dim3(1), dim3(64), 0, stream>>>(gold, sume, tgt_tok, (float*)d_out);
}

// Round 2
// 7644.807 us; speedup vs baseline: 1.2078x; 1.0311x over previous
//
#include <hip/hip_runtime.h>

typedef __attribute__((ext_vector_type(8))) short short8;
typedef __attribute__((ext_vector_type(4))) float f32x4;
typedef __attribute__((ext_vector_type(4))) unsigned int uint4v;
typedef unsigned short u16;

#define DEVI static __device__ __forceinline__

constexpr int TTm = 64;     // seq len (src & tgt)
constexpr int BBm = 64;     // batch
constexpr int EEm = 512;    // embed dim
constexpr int HHm = 1024;   // hidden
constexpr int GGm = 4096;   // 4*H
constexpr int TDm = 63;     // decoder steps

// ---------- small helpers ----------
DEVI u16 f2b(float f) {  // fp32 -> bf16 RNE
  unsigned u = __builtin_bit_cast(unsigned, f);
  return (u16)((u + 0x7fffu + ((u >> 16) & 1u)) >> 16);
}
DEVI float b2f(u16 h) { return __builtin_bit_cast(float, (unsigned)h << 16); }
DEVI float sigm(float x) { return 1.0f / (1.0f + __expf(-x)); }
DEVI float tanh_(float x) { return 1.0f - 2.0f / (1.0f + __expf(2.0f * x)); }

DEVI short8 cvt8(const float* p) {
  f32x4 x0 = *(const f32x4*)p;
  f32x4 x1 = *(const f32x4*)(p + 4);
  short8 r;
#pragma unroll
  for (int i = 0; i < 4; ++i) { r[i] = (short)f2b(x0[i]); r[i + 4] = (short)f2b(x1[i]); }
  return r;
}
DEVI void stage32_f32(short* dst, const float* src) {
#pragma unroll
  for (int i = 0; i < 4; ++i) *(short8*)&dst[i * 8] = cvt8(src + i * 8);
}
DEVI void stage32_b16(short* dst, const u16* src) {
#pragma unroll
  for (int i = 0; i < 4; ++i) *(uint4v*)&dst[i * 8] = *(const uint4v*)(src + i * 8);
}

// system-scope write-through 2B store: visible agent-wide once vmcnt retires.
DEVI void st_sys_b16(u16* p, u16 v) {
  unsigned d = v;
  asm volatile("global_store_short %0, %1, off sc0 sc1" :: "v"(p), "v"(d) : "memory");
}

// ---------- master-release grid barrier ----------
// Arrival: own-slot store (256 distinct lines, parallel, once per phase).
// Poll: ONLY block 0 reads the 256 arrival flags; it then publishes one
// monotone `go` word. All other blocks poll that single line with one lane.
// This removes the O(blocks^2) LLC line-request storm of all-poll-all.
// Data protection unchanged: sc0/sc1 write-through + vmcnt(0) drain before
// arrival; consumers read fresh (time-rotated) addresses -> never stale.
DEVI void gbar(unsigned* flags, unsigned phase) {
  unsigned* go = flags + 4096;  // byte offset 16384: own cache line
  asm volatile("s_waitcnt vmcnt(0)" ::: "memory");
  __syncthreads();
  if (threadIdx.x == 0) {
    __hip_atomic_store(&flags[blockIdx.x * 16], phase, __ATOMIC_RELAXED,
                       __HIP_MEMORY_SCOPE_AGENT);
  }
  if (blockIdx.x == 0) {
    if (threadIdx.x < 64) {
      const int i0 = threadIdx.x * 4;
      for (;;) {
        int ok = 1;
#pragma unroll
        for (int i = 0; i < 4; ++i) {
          unsigned v = __hip_atomic_load(&flags[(i0 + i) * 16], __ATOMIC_RELAXED,
                                         __HIP_MEMORY_SCOPE_AGENT);
          ok &= (v >= phase);
        }
        if (__all(ok)) break;
        __builtin_amdgcn_s_sleep(1);
      }
      if (threadIdx.x == 0)
        __hip_atomic_store(go, phase, __ATOMIC_RELAXED, __HIP_MEMORY_SCOPE_AGENT);
    }
  } else if (threadIdx.x == 0) {
    while (__hip_atomic_load(go, __ATOMIC_RELAXED, __HIP_MEMORY_SCOPE_AGENT) < phase)
      __builtin_amdgcn_s_sleep(2);
  }
  asm volatile("" ::: "memory");  // no hoisting loads above the poll
  __syncthreads();
}

// one BK=64 step of a 64x64 tile; 2 waves, wave wv owns cols [wv*32, wv*32+32)
DEVI void mfma_bk64(const short* As, const short* Bs, f32x4 acc[4][2], int wv, int ln) {
  const int l15 = ln & 15;
#pragma unroll
  for (int ks = 0; ks < 64; ks += 32) {
    const int kq = ks + ((ln >> 4) << 3);
    short8 b0 = *(const short8*)&Bs[(wv * 32 + l15) * 72 + kq];
    short8 b1 = *(const short8*)&Bs[(wv * 32 + 16 + l15) * 72 + kq];
#pragma unroll
    for (int mt = 0; mt < 4; ++mt) {
      short8 a = *(const short8*)&As[(mt * 16 + l15) * 72 + kq];
      acc[mt][0] = __builtin_amdgcn_mfma_f32_16x16x32_bf16(a, b0, acc[mt][0], 0, 0, 0);
      acc[mt][1] = __builtin_amdgcn_mfma_f32_16x16x32_bf16(a, b1, acc[mt][1], 0, 0, 0);
    }
  }
}

// ---------- setup ----------
__global__ void k_zero(uint4v* p, int n16) {
  int i = blockIdx.x * blockDim.x + threadIdx.x;
  uint4v z = {0u, 0u, 0u, 0u};
  for (; i < n16; i += gridDim.x * blockDim.x) p[i] = z;
}

__global__ void k_cvt_all(const float* Wihf, const float* Wihb, const float* Whhf,
                          const float* Whhb, const float* Wihd, const float* Whhd,
                          const float* Watt, const float* Whp, const float* Wcp,
                          const float* Wcomb, const float* Wvoc,
                          u16* o_ihf, u16* o_ihb, u16* o_hhf, u16* o_hhb,
                          u16* o_cat1, u16* o_cat2,
                          u16* o_att, u16* o_hp, u16* o_cp, u16* o_comb, u16* o_voc) {
  long i = (long)blockIdx.x * blockDim.x + threadIdx.x;
  const long stride = (long)gridDim.x * blockDim.x;
  for (; i < 65273856L; i += stride) {
    long r = i;
    if (r < 2097152) { o_ihf[r] = f2b(Wihf[r]); continue; } r -= 2097152;
    if (r < 2097152) { o_ihb[r] = f2b(Wihb[r]); continue; } r -= 2097152;
    if (r < 4194304) { o_hhf[r] = f2b(Whhf[r]); continue; } r -= 4194304;
    if (r < 4194304) { o_hhb[r] = f2b(Whhb[r]); continue; } r -= 4194304;
    if (r < 2097152) {  // cat1: W_ih_d[:, 0:512]
      long g = r >> 9, c = r & 511;
      o_cat1[r] = f2b(Wihd[g * 1536 + c]); continue;
    } r -= 2097152;
    if (r < 8388608) {  // cat2 row g = [W_ih_d[g][512:1536] | W_hh_d[g][:]]
      long g = r >> 11, c = r & 2047;
      o_cat2[r] = f2b(c < 1024 ? Wihd[g * 1536 + 512 + c] : Whhd[g * 1024 + (c - 1024)]);
      continue;
    } r -= 8388608;
    if (r < 2097152) { o_att[r] = f2b(Watt[r]); continue; } r -= 2097152;
    if (r < 2097152) { o_hp[r] = f2b(Whp[r]); continue; } r -= 2097152;
    if (r < 2097152) { o_cp[r] = f2b(Wcp[r]); continue; } r -= 2097152;
    if (r < 3145728) { o_comb[r] = f2b(Wcomb[r]); continue; } r -= 3145728;
    o_voc[r] = f2b(Wvoc[r]);
  }
}

// ---------- input-precompute: pre = emb[tok] @ W^T + bi + bh  (grid = (T, 64)) ----------
__global__ __launch_bounds__(128) void k_pre(
    const int* tok, const float* emb, const u16* W,
    const float* bi, const float* bh, u16* pre) {
  __shared__ short As[64 * 72], Bs[64 * 72];
  const int rt = blockIdx.x, ct = blockIdx.y;
  const int tid = threadIdx.x, wv = tid >> 6, sr = tid & 63, seg = tid >> 6;
  const int token = tok[rt * 64 + sr];
  const float* arow = emb + (long)token * EEm;
  const u16* brow = W + (long)(ct * 64 + sr) * EEm;
  f32x4 acc[4][2] = {};
  for (int k0 = 0; k0 < EEm; k0 += 64) {
    __syncthreads();
    stage32_f32(&As[sr * 72 + seg * 32], arow + k0 + seg * 32);
    stage32_b16(&Bs[sr * 72 + seg * 32], brow + k0 + seg * 32);
    __syncthreads();
    mfma_bk64(As, Bs, acc, wv, sr);
  }
  const int l15 = sr & 15, q = sr >> 4;
#pragma unroll
  for (int nt = 0; nt < 2; ++nt) {
    const int col = ct * 64 + wv * 32 + nt * 16 + l15;
    const float bias = bi[col] + bh[col];
#pragma unroll
    for (int mt = 0; mt < 4; ++mt)
#pragma unroll
      for (int r = 0; r < 4; ++r)
        pre[(long)(rt * 64 + mt * 16 + q * 4 + r) * GGm + col] = f2b(acc[mt][nt][r] + bias);
  }
}

// ---------- plain NT GEMM: C[M x (gridDim.y*64)] = A(bf16) * B(bf16,ldb)^T ----------
template <bool OUTB16>
__global__ __launch_bounds__(128) void k_gemm_plain(const u16* A, const u16* Bm,
                                                    void* C, int K, int ldb) {
  __shared__ short As[64 * 72], Bs[64 * 72];
  const int rt = blockIdx.x, ct = blockIdx.y;
  const int tid = threadIdx.x, wv = tid >> 6, sr = tid & 63, seg = tid >> 6;
  const u16* arow = A + (long)(rt * 64 + sr) * K;
  const u16* brow = Bm + (long)(ct * 64 + sr) * ldb;
  f32x4 acc[4][2] = {};
  for (int k0 = 0; k0 < K; k0 += 64) {
    __syncthreads();
    stage32_b16(&As[sr * 72 + seg * 32], arow + k0 + seg * 32);
    stage32_b16(&Bs[sr * 72 + seg * 32], brow + k0 + seg * 32);
    __syncthreads();
    mfma_bk64(As, Bs, acc, wv, sr);
  }
  const int l15 = sr & 15, q = sr >> 4, ldc = gridDim.y * 64;
#pragma unroll
  for (int nt = 0; nt < 2; ++nt) {
    const int col = ct * 64 + wv * 32 + nt * 16 + l15;
#pragma unroll
    for (int mt = 0; mt < 4; ++mt)
#pragma unroll
      for (int r = 0; r < 4; ++r) {
        const long idx = (long)(rt * 64 + mt * 16 + q * 4 + r) * ldc + col;
        if (OUTB16) ((u16*)C)[idx] = f2b(acc[mt][nt][r]);
        else        ((float*)C)[idx] = acc[mt][nt][r];
      }
  }
}

// ---------- cooperative encoder: all 64 time steps, both directions ----------
// h rotates through 64 time-indexed slots (slot s = h before step s): every
// consumer load is first-touch -> plain cached loads are never stale.
__global__ __launch_bounds__(256) void k_enc_all(
    const u16* __restrict__ Whhf, const u16* __restrict__ Whhb,
    const u16* __restrict__ pre_f, const u16* __restrict__ pre_b,
    const int* __restrict__ lens,
    u16* hist_f, u16* hist_b, u16* ench, u16* hcat, u16* ccat, unsigned* bar) {
  __shared__ float gshE[4 * 64 * 33];  // per-wave K-partials
  const int blk = blockIdx.x;
  const int dir = blk >> 7, jt = blk & 127, j0 = jt * 8;
  const u16* Whh = dir ? Whhb : Whhf;
  const u16* pre = dir ? pre_b : pre_f;
  u16* hist = dir ? hist_b : hist_f;
  const int tid = threadIdx.x, wv = tid >> 6, ln = tid & 63;
  const int l15 = ln & 15, half = ln >> 4;
  // B fragments: wave wv owns ksteps i*4+wv, i in 0..7 (K=1024 -> 32 ksteps)
  short8 bf[8][2];
#pragma unroll
  for (int i = 0; i < 8; ++i) {
    const int k = (i * 4 + wv) * 32 + half * 8;
#pragma unroll
    for (int nt = 0; nt < 2; ++nt) {
      const int n = nt * 16 + l15, g = n >> 3, jj = n & 7;
      bf[i][nt] = *(const short8*)(Whh + (long)(g * 1024 + j0 + jj) * 1024 + k);
    }
  }
  const int cb = tid & 63, cj = tid >> 6;  // cell: (batch cb, cols cj & cj+4)
  const int len_b = lens[cb];
  float creg[2] = {0.f, 0.f};
  u16 hlast[2] = {0, 0};
  for (int s = 0; s < 64; ++s) {
    const int t = dir ? (63 - s) : s;
    const u16* hcur = hist + s * 65536;
    u16* hnxt = hist + (s + 1) * 65536;
    f32x4 acc[4][2] = {};
#pragma unroll
    for (int i = 0; i < 8; ++i) {
      const int k = (i * 4 + wv) * 32 + half * 8;
#pragma unroll
      for (int mt = 0; mt < 4; ++mt) {
        short8 a = *(const short8*)(hcur + (mt * 16 + l15) * 1024 + k);
        acc[mt][0] = __builtin_amdgcn_mfma_f32_16x16x32_bf16(a, bf[i][0], acc[mt][0], 0, 0, 0);
        acc[mt][1] = __builtin_amdgcn_mfma_f32_16x16x32_bf16(a, bf[i][1], acc[mt][1], 0, 0, 0);
      }
    }
    __syncthreads();
#pragma unroll
    for (int mt = 0; mt < 4; ++mt)
#pragma unroll
      for (int nt = 0; nt < 2; ++nt)
#pragma unroll
        for (int r = 0; r < 4; ++r)
          gshE[wv * 2112 + (mt * 16 + half * 4 + r) * 33 + nt * 16 + l15] = acc[mt][nt][r];
    __syncthreads();
#pragma unroll
    for (int u = 0; u < 2; ++u) {
      const int jj = cj + u * 4, j = j0 + jj;
      float g4[4];
#pragma unroll
      for (int g = 0; g < 4; ++g) {
        const int n = g * 8 + jj;
        float v = gshE[cb * 33 + n] + gshE[2112 + cb * 33 + n] +
                  gshE[2 * 2112 + cb * 33 + n] + gshE[3 * 2112 + cb * 33 + n];
        v += b2f(pre[((long)t * 64 + cb) * GGm + g * 1024 + j]);
        g4[g] = v;
      }
      const float cold = creg[u];
      const float c2 = sigm(g4[1]) * cold + sigm(g4[0]) * tanh_(g4[2]);
      const float h2 = sigm(g4[3]) * tanh_(c2);
      const bool m = t < len_b;
      creg[u] = m ? c2 : cold;
      const u16 hv = m ? f2b(h2) : hcur[cb * 1024 + j];  // hcur line is L2-hot (A-loads)
      if (s < 63) st_sys_b16(&hnxt[cb * 1024 + j], hv);  // write-through publish
      else        hlast[u] = hv;                         // final h kept in regs
      ench[((long)cb * 64 + t) * 2048 + dir * 1024 + j] = f2b(m ? h2 : 0.f);
    }
    if (s < 63) gbar(bar, s + 1);
  }
  // epilogue: final states from registers — no post-loop coherence needed
#pragma unroll
  for (int u = 0; u < 2; ++u) {
    const int j = j0 + cj + u * 4;
    hcat[cb * 2048 + dir * 1024 + j] = hlast[u];
    ccat[cb * 2048 + dir * 1024 + j] = f2b(creg[u]);
  }
}

// ---------- cooperative decoder: all 63 steps, 2 barriers/step ----------
// h_hist slot t   = decoder h entering step t   (slot 0 = h0 from k_gemm_plain)
// o_hist slot t   = O entering step t           (slot 0 = zeros)
// o_hist slot t+1 doubles as outs[t] for the vocab kernels.
__global__ __launch_bounds__(256) void k_dec_all(
    const u16* __restrict__ Wcat2, const u16* __restrict__ Wcomb,
    const u16* __restrict__ y_pre, const u16* __restrict__ eproj,
    const u16* __restrict__ encW, const int* __restrict__ lens,
    u16* h_hist, const float* c_d, u16* o_hist, unsigned* bar) {
  __shared__ float gsh[4 * 64 * 17];
  __shared__ float h2s[1024];
  __shared__ float part[256];
  __shared__ float alph[64];
  const int blk = blockIdx.x, tid = threadIdx.x, wv = tid >> 6, ln = tid & 63;
  const int l15 = ln & 15, half = ln >> 4;
  const int j0 = blk * 4;
  // gates B-frags: K=2048 -> 64 ksteps, 16 per wave
  short8 bg[16];
#pragma unroll
  for (int i = 0; i < 16; ++i) {
    const int k = (i * 4 + wv) * 32 + half * 8;
    const int g = l15 >> 2, jj = l15 & 3;
    bg[i] = *(const short8*)(Wcat2 + (long)(g * 1024 + j0 + jj) * 2048 + k);
  }
  const int cb = tid & 63, cj = tid >> 6;  // (batch cb, col cj)
  const int ab = blk & 63, aq = blk >> 6;  // A' assignment
  const int len_ab = lens[ab];
  float creg = c_d[cb * 1024 + j0 + cj];
  unsigned phase = 0;
  for (int t = 0; t < TDm; ++t) {
    const u16* hprev = h_hist + t * 65536;
    u16* hnew = h_hist + (t + 1) * 65536;
    const u16* o_prev = o_hist + t * 65536;
    u16* o_out = o_hist + (t + 1) * 65536;
    // ---- phase G: gates GEMM + cell ----
    f32x4 acc[4] = {};
#pragma unroll
    for (int i = 0; i < 16; ++i) {
      const int k = (i * 4 + wv) * 32 + half * 8;
      const u16* asrc = (k < 1024) ? (o_prev + k) : (hprev + (k - 1024));
#pragma unroll
      for (int mt = 0; mt < 4; ++mt) {
        short8 a = *(const short8*)(asrc + (mt * 16 + l15) * 1024);
        acc[mt] = __builtin_amdgcn_mfma_f32_16x16x32_bf16(a, bg[i], acc[mt], 0, 0, 0);
      }
    }
    __syncthreads();
#pragma unroll
    for (int mt = 0; mt < 4; ++mt)
#pragma unroll
      for (int r = 0; r < 4; ++r)
        gsh[wv * 1088 + (mt * 16 + half * 4 + r) * 17 + l15] = acc[mt][r];
    __syncthreads();
    {
      float g4[4];
#pragma unroll
      for (int g = 0; g < 4; ++g) {
        const int n = g * 4 + cj;
        float v = gsh[cb * 17 + n] + gsh[1088 + cb * 17 + n] +
                  gsh[2 * 1088 + cb * 17 + n] + gsh[3 * 1088 + cb * 17 + n];
        v += b2f(y_pre[((long)t * 64 + cb) * GGm + g * 1024 + j0 + cj]);
        g4[g] = v;
      }
      const float c2 = sigm(g4[1]) * creg + sigm(g4[0]) * tanh_(g4[2]);
      const float h2 = sigm(g4[3]) * tanh_(c2);
      creg = c2;
      st_sys_b16(&hnew[cb * 1024 + j0 + cj], f2b(h2));  // write-through publish
    }
    gbar(bar, ++phase);
    // ---- phase A': attention + combine + tanh ----
    for (int i = tid; i < 1024; i += 256) h2s[i] = b2f(hnew[ab * 1024 + i]);
    __syncthreads();
    {  // scores (redundant across the 4 q-blocks of batch ab)
      const int tt = tid >> 2, qq = tid & 3;
      const u16* row = eproj + ((long)ab * 64 + tt) * 1024 + qq * 256;
      float a0 = 0.f;
      for (int i = 0; i < 256; i += 8) {
        uint4v v = *(const uint4v*)(row + i);
        const u16* pv = (const u16*)&v;
#pragma unroll
        for (int j = 0; j < 8; ++j) a0 += b2f(pv[j]) * h2s[qq * 256 + i + j];
      }
      part[tid] = a0;
    }
    __syncthreads();
    if (tid < 64) {
      float e = part[tid * 4] + part[tid * 4 + 1] + part[tid * 4 + 2] + part[tid * 4 + 3];
      e = (tid < len_ab) ? e : -INFINITY;
      float mx = e;
#pragma unroll
      for (int m = 1; m < 64; m <<= 1) mx = fmaxf(mx, __shfl_xor(mx, m));
      float p = __expf(e - mx);
      float s = p;
#pragma unroll
      for (int m = 1; m < 64; m <<= 1) s += __shfl_xor(s, m);
      alph[tid] = p / s;
    }
    __syncthreads();
    {
      const int j = aq * 256 + tid;
      float oa = 0.f;
      for (int tt = 0; tt < 64; ++tt) {
        const float al = alph[tt];
        if (al != 0.f) oa += al * b2f(encW[((long)ab * 64 + tt) * 1024 + j]);
      }
      float oh = 0.f;
      const u16* wrow = Wcomb + (long)j * 3072 + 2048;
      for (int k = 0; k < 1024; k += 8) {
        uint4v v = *(const uint4v*)(wrow + k);
        const u16* pv = (const u16*)&v;
#pragma unroll
        for (int jj = 0; jj < 8; ++jj) oh += b2f(pv[jj]) * h2s[k + jj];
      }
      const u16 ob = f2b(tanh_(oa + oh));
      st_sys_b16(&o_out[ab * 1024 + j], ob);  // single store: O state + outs[t]
    }
    if (t < TDm - 1) gbar(bar, ++phase);
  }
}

// ---------- vocab projection: streaming sum(exp(logit)) ----------
__global__ __launch_bounds__(128) void k_vocab(const u16* outs, const u16* Wvoc,
                                               float* sumexp) {
  __shared__ short As[64 * 72], Bs[64 * 72];
  const int vt = blockIdx.x, t = blockIdx.y;
  const int tid = threadIdx.x, wv = tid >> 6, sr = tid & 63, seg = tid >> 6;
  const u16* arow = outs + ((long)t * 64 + sr) * 1024;
  const u16* brow = Wvoc + (long)(vt * 64 + sr) * 1024;
  f32x4 acc[4][2] = {};
  for (int k0 = 0; k0 < 1024; k0 += 64) {
    __syncthreads();
    stage32_b16(&As[sr * 72 + seg * 32], arow + k0 + seg * 32);
    stage32_b16(&Bs[sr * 72 + seg * 32], brow + k0 + seg * 32);
    __syncthreads();
    mfma_bk64(As, Bs, acc, wv, sr);
  }
  const int l15 = sr & 15, q = sr >> 4;
#pragma unroll
  for (int mt = 0; mt < 4; ++mt)
#pragma unroll
    for (int r = 0; r < 4; ++r) {
      float e = __expf(acc[mt][0][r]) + __expf(acc[mt][1][r]);
      e += __shfl_xor(e, 1); e += __shfl_xor(e, 2);
      e += __shfl_xor(e, 4); e += __shfl_xor(e, 8);
      if (l15 == 0) atomicAdd(&sumexp[t * 64 + mt * 16 + q * 4 + r], e);
    }
}

__global__ __launch_bounds__(256) void k_gold(const u16* outs, const u16* Wvoc,
                                              const int* tgt, float* gold) {
  const int t = blockIdx.x;
  const int wv = threadIdx.x >> 6, ln = threadIdx.x & 63;
  for (int b = wv; b < 64; b += 4) {
    const int g = tgt[(t + 1) * 64 + b];
    const u16* o = outs + ((long)t * 64 + b) * 1024 + ln * 16;
    const u16* w = Wvoc + (long)g * 1024 + ln * 16;
    uint4v v0 = *(const uint4v*)o, v1 = *(const uint4v*)(o + 8);
    uint4v w0 = *(const uint4v*)w, w1 = *(const uint4v*)(w + 8);
    const u16 *pv0 = (const u16*)&v0, *pv1 = (const u16*)&v1;
    const u16 *pw0 = (const u16*)&w0, *pw1 = (const u16*)&w1;
    float acc = 0.f;
#pragma unroll
    for (int j = 0; j < 8; ++j)
      acc += b2f(pv0[j]) * b2f(pw0[j]) + b2f(pv1[j]) * b2f(pw1[j]);
#pragma unroll
    for (int m = 1; m < 64; m <<= 1) acc += __shfl_xor(acc, m);
    if (ln == 0) gold[t * 64 + b] = acc;
  }
}

__global__ void k_final(const float* gold, const float* sumexp, const int* tgt,
                        float* out) {
  const int b = threadIdx.x;
  float s = 0.f;
  for (int t = 0; t < TDm; ++t)
    if (tgt[(t + 1) * 64 + b] != 0)
      s += gold[t * 64 + b] - logf(sumexp[t * 64 + b]);
  out[b] = s;
}

// ---------- host ----------
extern "C" void kernel_launch(void* const* d_in, const int* in_sizes, int n_in,
                              void* d_out, int out_size, void* d_ws, size_t ws_size,
                              hipStream_t stream) {
  const int* src_tok = (const int*)d_in[0];
  const int* tgt_tok = (const int*)d_in[1];
  const int* lens    = (const int*)d_in[2];
  const float* semb  = (const float*)d_in[3];
  const float* demb  = (const float*)d_in[4];
  const float* Wihf  = (const float*)d_in[5];
  const float* Whhf  = (const float*)d_in[6];
  const float* bihf  = (const float*)d_in[7];
  const float* bhhf  = (const float*)d_in[8];
  const float* Wihb  = (const float*)d_in[9];
  const float* Whhb  = (const float*)d_in[10];
  const float* bihb  = (const float*)d_in[11];
  const float* bhhb  = (const float*)d_in[12];
  const float* Wihd  = (const float*)d_in[13];
  const float* Whhd  = (const float*)d_in[14];
  const float* bihd  = (const float*)d_in[15];
  const float* bhhd  = (const float*)d_in[16];
  const float* Whp   = (const float*)d_in[17];
  const float* Wcp   = (const float*)d_in[18];
  const float* Watt  = (const float*)d_in[19];
  const float* Wcomb = (const float*)d_in[20];
  const float* Wvoc  = (const float*)d_in[21];

  char* w = (char*)d_ws;
  auto alloc = [&](size_t bytes) { char* p = w; w += (bytes + 255) & ~(size_t)255; return p; };
  // zero-span (contiguous): encoder h histories, decoder o history, sume, barriers
  u16* histF  = (u16*)alloc(8388608);    // 64 slots x (64x1024) bf16; slot0 = h=0
  u16* histB  = (u16*)alloc(8388608);
  u16* o_hist = (u16*)alloc(8388608);    // 64 slots; slot0 = O(-1)=0; slot t+1 = outs[t]
  float* sume = (float*)alloc(16384);
  unsigned* barE = (unsigned*)alloc(32768);   // 256 flags x 64B + go word @ +16384
  unsigned* barD = (unsigned*)alloc(32768);
  const int zero16 = (int)((w - (char*)histF) / 16);
  float* gold   = (float*)alloc(16384);
  float* c_d    = (float*)alloc(262144);
  u16* h_hist   = (u16*)alloc(8388608);  // decoder h: 64 slots; slot0 = h0
  u16* hcat     = (u16*)alloc(262144);
  u16* ccat     = (u16*)alloc(262144);
  u16* Wb_ihf   = (u16*)alloc(4194304);
  u16* Wb_ihb   = (u16*)alloc(4194304);
  u16* Wb_hhf   = (u16*)alloc(8388608);
  u16* Wb_hhb   = (u16*)alloc(8388608);
  u16* Wb_cat1  = (u16*)alloc(4194304);
  u16* Wb_cat2  = (u16*)alloc(16777216);
  u16* Wb_att   = (u16*)alloc(4194304);
  u16* Wb_hp    = (u16*)alloc(4194304);
  u16* Wb_cp    = (u16*)alloc(4194304);
  u16* Wb_comb  = (u16*)alloc(6291456);
  u16* Wb_voc   = (u16*)alloc(65536000);
  u16* pre_f    = (u16*)alloc(33554432);
  u16* pre_b    = (u16*)alloc(33554432);
  u16* y_pre    = (u16*)alloc(33030144);  // 63*64*4096 bf16
  u16* ench     = (u16*)alloc(16777216);  // (b, t, 2048) bf16
  u16* eproj    = (u16*)alloc(8388608);   // (b, t, 1024) bf16
  u16* encW     = (u16*)alloc(8388608);   // (b, t, 1024) bf16
  u16* outs     = o_hist + 65536;         // view: slot t+1 of o_hist = outs[t]

  k_zero<<<dim3(256), dim3(256), 0, stream>>>((uint4v*)histF, zero16);
  k_cvt_all<<<dim3(2048), dim3(256), 0, stream>>>(
      Wihf, Wihb, Whhf, Whhb, Wihd, Whhd, Watt, Whp, Wcp, Wcomb, Wvoc,
      Wb_ihf, Wb_ihb, Wb_hhf, Wb_hhb, Wb_cat1, Wb_cat2,
      Wb_att, Wb_hp, Wb_cp, Wb_comb, Wb_voc);
  k_pre<<<dim3(64, 64), dim3(128), 0, stream>>>(src_tok, semb, Wb_ihf, bihf, bhhf, pre_f);
  k_pre<<<dim3(64, 64), dim3(128), 0, stream>>>(src_tok, semb, Wb_ihb, bihb, bhhb, pre_b);
  k_pre<<<dim3(63, 64), dim3(128), 0, stream>>>(tgt_tok, demb, Wb_cat1, bihd, bhhd, y_pre);
  {
    void* args[] = {(void*)&Wb_hhf, (void*)&Wb_hhb, (void*)&pre_f, (void*)&pre_b,
                    (void*)&lens, (void*)&histF, (void*)&histB, (void*)&ench,
                    (void*)&hcat, (void*)&ccat, (void*)&barE};
    hipLaunchCooperativeKernel((void*)k_enc_all, dim3(256), dim3(256), args, 0, stream);
  }
  k_gemm_plain<true><<<dim3(1, 16), dim3(128), 0, stream>>>(hcat, Wb_hp, (void*)h_hist, 2048, 2048);
  k_gemm_plain<false><<<dim3(1, 16), dim3(128), 0, stream>>>(ccat, Wb_cp, (void*)c_d, 2048, 2048);
  k_gemm_plain<true><<<dim3(64, 16), dim3(128), 0, stream>>>(ench, Wb_att, (void*)eproj, 2048, 2048);
  k_gemm_plain<true><<<dim3(64, 16), dim3(128), 0, stream>>>(ench, Wb_comb, (void*)encW, 2048, 3072);
  {
    void* args[] = {(void*)&Wb_cat2, (void*)&Wb_comb, (void*)&y_pre, (void*)&eproj,
                    (void*)&encW, (void*)&lens, (void*)&h_hist, (void*)&c_d,
                    (void*)&o_hist, (void*)&barD};
    hipLaunchCooperativeKernel((void*)k_dec_all, dim3(256), dim3(256), args, 0, stream);
  }
  k_vocab<<<dim3(500, 63), dim3(128), 0, stream>>>(outs, Wb_voc, sume);
  k_gold<<<dim3(63), dim3(256), 0, stream>>>(outs, Wb_voc, tgt_tok, gold);
  k_final<<<dim3(1), dim3(64), 0, stream>>>(gold, sume, tgt_tok, (float*)d_out);
}